// Round 4
// baseline (165.471 us; speedup 1.0000x reference)
//
#include <hip/hip_runtime.h>
#include <hip/hip_bf16.h>

#define NTOK 1024
#define EMB  1024
#define NH   16
#define HD   64
#define NS   128

typedef unsigned short u16;
typedef __attribute__((ext_vector_type(8))) short short8v;
typedef __attribute__((ext_vector_type(8))) unsigned short ushort8v;
typedef __attribute__((ext_vector_type(4))) float f32x4;

__device__ __forceinline__ u16 f2bf(float f) {
  union { float f; unsigned u; } x; x.f = f;
  return (u16)((x.u + 0x7FFFu + ((x.u >> 16) & 1u)) >> 16);
}
__device__ __forceinline__ float bf2f(u16 u) {
  union { unsigned u; float f; } x; x.u = ((unsigned)u) << 16;
  return x.f;
}
__device__ __forceinline__ float readlane_f(float v, int l) {
  union { float f; int i; } x; x.f = v;
  x.i = __builtin_amdgcn_readlane(x.i, l);
  return x.f;
}

// ---------------------------------------------------------------------------
// QKV GEMM: C[M,N] = A[M,K] * B[N,K]^T + bias[N], M=N=K=1024.
// A fp32, out bf16. 128x128 tile, BK=32, 256 threads, mfma 16x16x32 bf16.
// LDS row stride 56 elems = 112 B. blockIdx.z selects (A,B,bias) triple.
// ---------------------------------------------------------------------------
__global__ __launch_bounds__(256) void gemm_mfma(
    const float* __restrict__ A0, const float* __restrict__ A1, const float* __restrict__ A2,
    const float* __restrict__ B0, const float* __restrict__ B1, const float* __restrict__ B2,
    const float* __restrict__ b0, const float* __restrict__ b1, const float* __restrict__ b2,
    u16* __restrict__ Cp) {
  __shared__ u16 As[128 * 56];
  __shared__ u16 Bs[128 * 56];

  const int t = threadIdx.x;
  const int lane = t & 63;
  const int w = t >> 6;
  const int wr = w >> 1, wc = w & 1;
  const int m0 = blockIdx.y * 128;
  const int n0 = blockIdx.x * 128;
  const int z = blockIdx.z;

  const float* Asel = (z == 0) ? A0 : ((z == 1) ? A1 : A2);
  const float* Bsel = (z == 0) ? B0 : ((z == 1) ? B1 : B2);
  const float* bsel = (z == 0) ? b0 : ((z == 1) ? b1 : b2);

  const int srow = t >> 1;
  const int scol = (t & 1) * 16;

  f32x4 acc[4][4];
#pragma unroll
  for (int m = 0; m < 4; m++)
#pragma unroll
    for (int n = 0; n < 4; n++) acc[m][n] = (f32x4){0.f, 0.f, 0.f, 0.f};

  const int fr = lane & 15;
  const int fq = lane >> 4;
  const int kq = fq * 8;

  for (int k0 = 0; k0 < 1024; k0 += 32) {
    {
      const float* ap = Asel + (size_t)(m0 + srow) * 1024 + k0 + scol;
      const float4 f0 = ((const float4*)ap)[0];
      const float4 f1 = ((const float4*)ap)[1];
      const float4 f2 = ((const float4*)ap)[2];
      const float4 f3 = ((const float4*)ap)[3];
      ushort8v p0, p1;
      p0[0] = f2bf(f0.x); p0[1] = f2bf(f0.y); p0[2] = f2bf(f0.z); p0[3] = f2bf(f0.w);
      p0[4] = f2bf(f1.x); p0[5] = f2bf(f1.y); p0[6] = f2bf(f1.z); p0[7] = f2bf(f1.w);
      p1[0] = f2bf(f2.x); p1[1] = f2bf(f2.y); p1[2] = f2bf(f2.z); p1[3] = f2bf(f2.w);
      p1[4] = f2bf(f3.x); p1[5] = f2bf(f3.y); p1[6] = f2bf(f3.z); p1[7] = f2bf(f3.w);
      *(ushort8v*)&As[srow * 56 + scol]     = p0;
      *(ushort8v*)&As[srow * 56 + scol + 8] = p1;
    }
    {
      const float* bp = Bsel + (size_t)(n0 + srow) * 1024 + k0 + scol;
      const float4 f0 = ((const float4*)bp)[0];
      const float4 f1 = ((const float4*)bp)[1];
      const float4 f2 = ((const float4*)bp)[2];
      const float4 f3 = ((const float4*)bp)[3];
      ushort8v p0, p1;
      p0[0] = f2bf(f0.x); p0[1] = f2bf(f0.y); p0[2] = f2bf(f0.z); p0[3] = f2bf(f0.w);
      p0[4] = f2bf(f1.x); p0[5] = f2bf(f1.y); p0[6] = f2bf(f1.z); p0[7] = f2bf(f1.w);
      p1[0] = f2bf(f2.x); p1[1] = f2bf(f2.y); p1[2] = f2bf(f2.z); p1[3] = f2bf(f2.w);
      p1[4] = f2bf(f3.x); p1[5] = f2bf(f3.y); p1[6] = f2bf(f3.z); p1[7] = f2bf(f3.w);
      *(ushort8v*)&Bs[srow * 56 + scol]     = p0;
      *(ushort8v*)&Bs[srow * 56 + scol + 8] = p1;
    }
    __syncthreads();

    short8v a[4], b[4];
#pragma unroll
    for (int m = 0; m < 4; m++)
      a[m] = *(const short8v*)&As[(wr * 64 + m * 16 + fr) * 56 + kq];
#pragma unroll
    for (int n = 0; n < 4; n++)
      b[n] = *(const short8v*)&Bs[(wc * 64 + n * 16 + fr) * 56 + kq];
#pragma unroll
    for (int m = 0; m < 4; m++)
#pragma unroll
      for (int n = 0; n < 4; n++)
        acc[m][n] = __builtin_amdgcn_mfma_f32_16x16x32_bf16(a[m], b[n], acc[m][n], 0, 0, 0);
    __syncthreads();
  }

  u16* Cb = Cp + (size_t)z * 1024 * 1024;
#pragma unroll
  for (int n = 0; n < 4; n++) {
    const int col = n0 + wc * 64 + n * 16 + fr;
    const float bn = bsel[col];
#pragma unroll
    for (int m = 0; m < 4; m++) {
      const int rbase = m0 + wr * 64 + m * 16 + fq * 4;
#pragma unroll
      for (int r = 0; r < 4; r++)
        Cb[(size_t)(rbase + r) * 1024 + col] = f2bf(acc[m][n][r] + bn);
    }
  }
}

// ---------------------------------------------------------------------------
// Output projection: C[M,N] = A[M,K]*B[N,K]^T + bias, A bf16, out fp32.
// 64x128 tile (BM=64, BN=128) -> 128 WGs for 2x CU residency at M=N=1024.
// ---------------------------------------------------------------------------
__global__ __launch_bounds__(256) void gemm64(const u16* __restrict__ A,
                                              const float* __restrict__ B,
                                              const float* __restrict__ bias,
                                              float* __restrict__ C) {
  __shared__ u16 As[64 * 56];
  __shared__ u16 Bs[128 * 56];

  const int t = threadIdx.x;
  const int lane = t & 63;
  const int w = t >> 6;
  const int wr = w >> 1, wc = w & 1;
  const int m0 = blockIdx.y * 64;
  const int n0 = blockIdx.x * 128;

  const int sra = t >> 2;          // 0..63
  const int sca = (t & 3) * 8;     // 0,8,16,24
  const int srb = t >> 1;          // 0..127
  const int scb = (t & 1) * 16;

  f32x4 acc[2][4];
#pragma unroll
  for (int m = 0; m < 2; m++)
#pragma unroll
    for (int n = 0; n < 4; n++) acc[m][n] = (f32x4){0.f, 0.f, 0.f, 0.f};

  const int fr = lane & 15;
  const int fq = lane >> 4;
  const int kq = fq * 8;

  for (int k0 = 0; k0 < 1024; k0 += 32) {
    *(ushort8v*)&As[sra * 56 + sca] =
        *(const ushort8v*)(A + (size_t)(m0 + sra) * 1024 + k0 + sca);
    {
      const float* bp = B + (size_t)(n0 + srb) * 1024 + k0 + scb;
      const float4 f0 = ((const float4*)bp)[0];
      const float4 f1 = ((const float4*)bp)[1];
      const float4 f2 = ((const float4*)bp)[2];
      const float4 f3 = ((const float4*)bp)[3];
      ushort8v p0, p1;
      p0[0] = f2bf(f0.x); p0[1] = f2bf(f0.y); p0[2] = f2bf(f0.z); p0[3] = f2bf(f0.w);
      p0[4] = f2bf(f1.x); p0[5] = f2bf(f1.y); p0[6] = f2bf(f1.z); p0[7] = f2bf(f1.w);
      p1[0] = f2bf(f2.x); p1[1] = f2bf(f2.y); p1[2] = f2bf(f2.z); p1[3] = f2bf(f2.w);
      p1[4] = f2bf(f3.x); p1[5] = f2bf(f3.y); p1[6] = f2bf(f3.z); p1[7] = f2bf(f3.w);
      *(ushort8v*)&Bs[srb * 56 + scb]     = p0;
      *(ushort8v*)&Bs[srb * 56 + scb + 8] = p1;
    }
    __syncthreads();

    short8v a[2], b[4];
#pragma unroll
    for (int m = 0; m < 2; m++)
      a[m] = *(const short8v*)&As[(wr * 32 + m * 16 + fr) * 56 + kq];
#pragma unroll
    for (int n = 0; n < 4; n++)
      b[n] = *(const short8v*)&Bs[(wc * 64 + n * 16 + fr) * 56 + kq];
#pragma unroll
    for (int m = 0; m < 2; m++)
#pragma unroll
      for (int n = 0; n < 4; n++)
        acc[m][n] = __builtin_amdgcn_mfma_f32_16x16x32_bf16(a[m], b[n], acc[m][n], 0, 0, 0);
    __syncthreads();
  }

#pragma unroll
  for (int n = 0; n < 4; n++) {
    const int col = n0 + wc * 64 + n * 16 + fr;
    const float bn = bias[col];
#pragma unroll
    for (int m = 0; m < 2; m++) {
      const int rbase = m0 + wr * 32 + m * 16 + fq * 4;
#pragma unroll
      for (int r = 0; r < 4; r++)
        C[(size_t)(rbase + r) * 1024 + col] = acc[m][n][r] + bn;
    }
  }
}

// ---------------------------------------------------------------------------
// Per-token bitonic sort of the 128 sample indices -> sorted u16 cols.
// ---------------------------------------------------------------------------
__global__ __launch_bounds__(128) void sort_kernel(const int* __restrict__ samples,
                                                   u16* __restrict__ cols) {
  const int row = blockIdx.x;
  const int t = threadIdx.x;
  __shared__ int s[NS];
  s[t] = samples[(size_t)row * NS + t];
  __syncthreads();

  for (unsigned k = 2; k <= NS; k <<= 1) {
    for (unsigned j = k >> 1; j > 0; j >>= 1) {
      const unsigned ixj = t ^ j;
      if (ixj > (unsigned)t) {
        const int a = s[t], b = s[ixj];
        const bool up = ((t & k) == 0);
        if ((up && a > b) || (!up && a < b)) { s[t] = b; s[ixj] = a; }
      }
      __syncthreads();
    }
  }
  cols[(size_t)row * NS + t] = (u16)s[t];
}

// ---------------------------------------------------------------------------
// Attention: ONE WAVE per (token, head). 256-thread blocks = 4 independent
// waves, ZERO barriers. Block (g, i): wave w -> token i, head g*4+w.
//  lane l owns samples l and l+64; q row in 64 fp32 regs.
//  softmax fully in-wave (shfl_xor butterfly).
//  PV: lane = dim; weight/col broadcast via v_readlane (uniform -> SGPR);
//      4 accumulators per half for ILP; 128B/wave coalesced V loads.
// ---------------------------------------------------------------------------
__global__ __launch_bounds__(256) void attn3(const u16* __restrict__ Qb,
                                             const u16* __restrict__ Kb,
                                             const u16* __restrict__ Vb,
                                             const u16* __restrict__ cols,
                                             u16* __restrict__ O) {
  const int i = blockIdx.y;
  const int h = blockIdx.x * 4 + (threadIdx.x >> 6);
  const int lane = threadIdx.x & 63;

  // ---- sample columns + dup flags ----
  const int c0 = (int)cols[(size_t)i * NS + lane];
  const int c1 = (int)cols[(size_t)i * NS + 64 + lane];
  const int cp0 = __shfl_up(c0, 1, 64);
  int cp1 = __shfl_up(c1, 1, 64);
  const int c0_63 = __builtin_amdgcn_readlane(c0, 63);
  if (lane == 0) cp1 = c0_63;
  const bool dup0 = (lane > 0) && (c0 == cp0);
  const bool dup1 = (c1 == cp1);

  // ---- q row in registers ----
  float q[64];
  {
    const u16* qp = Qb + (size_t)i * EMB + h * HD;
#pragma unroll
    for (int j = 0; j < 8; j++) {
      const ushort8v v = *(const ushort8v*)(qp + j * 8);
#pragma unroll
      for (int e = 0; e < 8; e++) q[j * 8 + e] = bf2f(v[e]);
    }
  }

  // ---- scores for the two owned samples ----
  float s0 = 0.f, s1 = 0.f;
  {
    const u16* kp0 = Kb + (size_t)c0 * EMB + h * HD;
    const u16* kp1 = Kb + (size_t)c1 * EMB + h * HD;
#pragma unroll
    for (int j = 0; j < 8; j++) {
      const ushort8v k0v = *(const ushort8v*)(kp0 + j * 8);
      const ushort8v k1v = *(const ushort8v*)(kp1 + j * 8);
#pragma unroll
      for (int e = 0; e < 8; e++) {
        s0 += q[j * 8 + e] * bf2f(k0v[e]);
        s1 += q[j * 8 + e] * bf2f(k1v[e]);
      }
    }
  }
  s0 = dup0 ? -1e30f : s0 * 0.03125f;  // 1/sqrt(1024)
  s1 = dup1 ? -1e30f : s1 * 0.03125f;

  // ---- in-wave softmax over 128 values ----
  float mx = fmaxf(s0, s1);
#pragma unroll
  for (int off = 32; off > 0; off >>= 1) mx = fmaxf(mx, __shfl_xor(mx, off, 64));
  const float e0 = __expf(s0 - mx);
  const float e1 = __expf(s1 - mx);
  float sm = e0 + e1;
#pragma unroll
  for (int off = 32; off > 0; off >>= 1) sm += __shfl_xor(sm, off, 64);
  const float inv = 1.0f / sm;
  const float w0 = e0 * inv;
  const float w1 = e1 * inv;

  // ---- PV: lane = output dim ----
  const u16* vbase = Vb + h * HD + lane;
  float a0 = 0.f, a1 = 0.f, a2 = 0.f, a3 = 0.f;
  for (int sb = 0; sb < 64; sb += 4) {
    const int   ca = __builtin_amdgcn_readlane(c0, sb + 0);
    const int   cb = __builtin_amdgcn_readlane(c0, sb + 1);
    const int   cc = __builtin_amdgcn_readlane(c0, sb + 2);
    const int   cd = __builtin_amdgcn_readlane(c0, sb + 3);
    const float wa = readlane_f(w0, sb + 0);
    const float wb = readlane_f(w0, sb + 1);
    const float wc = readlane_f(w0, sb + 2);
    const float wd = readlane_f(w0, sb + 3);
    a0 += wa * bf2f(vbase[(size_t)ca * EMB]);
    a1 += wb * bf2f(vbase[(size_t)cb * EMB]);
    a2 += wc * bf2f(vbase[(size_t)cc * EMB]);
    a3 += wd * bf2f(vbase[(size_t)cd * EMB]);
  }
  for (int sb = 0; sb < 64; sb += 4) {
    const int   ca = __builtin_amdgcn_readlane(c1, sb + 0);
    const int   cb = __builtin_amdgcn_readlane(c1, sb + 1);
    const int   cc = __builtin_amdgcn_readlane(c1, sb + 2);
    const int   cd = __builtin_amdgcn_readlane(c1, sb + 3);
    const float wa = readlane_f(w1, sb + 0);
    const float wb = readlane_f(w1, sb + 1);
    const float wc = readlane_f(w1, sb + 2);
    const float wd = readlane_f(w1, sb + 3);
    a0 += wa * bf2f(vbase[(size_t)ca * EMB]);
    a1 += wb * bf2f(vbase[(size_t)cb * EMB]);
    a2 += wc * bf2f(vbase[(size_t)cc * EMB]);
    a3 += wd * bf2f(vbase[(size_t)cd * EMB]);
  }
  O[(size_t)i * EMB + h * HD + lane] = f2bf((a0 + a1) + (a2 + a3));
}

extern "C" void kernel_launch(void* const* d_in, const int* in_sizes, int n_in,
                              void* d_out, int out_size, void* d_ws, size_t ws_size,
                              hipStream_t stream) {
  const float* query = (const float*)d_in[0];
  const float* key   = (const float*)d_in[1];
  const float* value = (const float*)d_in[2];
  const float* Wq    = (const float*)d_in[3];
  const float* bq    = (const float*)d_in[4];
  const float* Wk    = (const float*)d_in[5];
  const float* bk    = (const float*)d_in[6];
  const float* Wv    = (const float*)d_in[7];
  const float* bv    = (const float*)d_in[8];
  const float* Wo    = (const float*)d_in[9];
  const float* bo    = (const float*)d_in[10];
  const int* samples = (const int*)d_in[11];
  float* out = (float*)d_out;

  // ws layout (bf16): Qb,Kb,Vb 3*2MB; O 2MB; cols 0.25MB => 8.25 MB total
  u16* Qb = (u16*)d_ws;
  u16* Kb = Qb + (size_t)NTOK * EMB;
  u16* Vb = Kb + (size_t)NTOK * EMB;
  u16* O  = Vb + (size_t)NTOK * EMB;
  u16* cols = O + (size_t)NTOK * EMB;

  sort_kernel<<<NTOK, NS, 0, stream>>>(samples, cols);

  gemm_mfma<<<dim3(8, 8, 3), 256, 0, stream>>>(
      query, key, value, Wq, Wk, Wv, bq, bk, bv, Qb);

  attn3<<<dim3(NH / 4, NTOK), 256, 0, stream>>>(Qb, Kb, Vb, cols, O);

  gemm64<<<dim3(8, 16), 256, 0, stream>>>(O, Wo, bo, out);
}

// Round 5
// 121.417 us; speedup vs baseline: 1.3628x; 1.3628x over previous
//
#include <hip/hip_runtime.h>
#include <hip/hip_bf16.h>

#define NTOK 1024
#define EMB  1024
#define NH   16
#define HD   64
#define NS   128

typedef unsigned short u16;
typedef unsigned int uint;
typedef __attribute__((ext_vector_type(8))) unsigned short ushort8v;
typedef __attribute__((ext_vector_type(8))) _Float16 half8v;
typedef __attribute__((ext_vector_type(2))) _Float16 h2;
typedef __attribute__((ext_vector_type(4))) float f32x4;

__device__ __forceinline__ u16 f2h_bits(float f) {
  union { _Float16 h; u16 u; } x; x.h = (_Float16)f; return x.u;
}

// ---------------------------------------------------------------------------
// GEMM: C[M,N] = A[M,K] * B[N,K]^T + bias[N], M=N=K=1024, f16 MFMA.
// 64x64 tile, BK=32, 256 threads (4 waves, 2x2 of 32x32), 16 MFMA/k-step.
// -> QKV: grid(16,16,3) = 768 WGs (3/CU); out-proj: grid(16,16,1) = 256 WGs.
// LDS row stride 56 u16 = 112 B (odd multiple of 16B).
// ---------------------------------------------------------------------------
template<bool A_F16, bool OUT_F16>
__global__ __launch_bounds__(256) void gemm_t64(
    const void* __restrict__ A0, const void* __restrict__ A1, const void* __restrict__ A2,
    const float* __restrict__ B0, const float* __restrict__ B1, const float* __restrict__ B2,
    const float* __restrict__ b0, const float* __restrict__ b1, const float* __restrict__ b2,
    void* __restrict__ Cp) {
  __shared__ u16 As[64 * 56];
  __shared__ u16 Bs[64 * 56];

  const int t = threadIdx.x;
  const int lane = t & 63;
  const int w = t >> 6;
  const int wr = w >> 1, wc = w & 1;
  const int m0 = blockIdx.y * 64;
  const int n0 = blockIdx.x * 64;
  const int z = blockIdx.z;

  const void*  Asel = (z == 0) ? A0 : ((z == 1) ? A1 : A2);
  const float* Bsel = (z == 0) ? B0 : ((z == 1) ? B1 : B2);
  const float* bsel = (z == 0) ? b0 : ((z == 1) ? b1 : b2);

  const int srow = t >> 2;         // 0..63
  const int scol = (t & 3) * 8;    // 0,8,16,24

  f32x4 acc[2][2];
#pragma unroll
  for (int m = 0; m < 2; m++)
#pragma unroll
    for (int n = 0; n < 2; n++) acc[m][n] = (f32x4){0.f, 0.f, 0.f, 0.f};

  const int fr = lane & 15;
  const int fq = lane >> 4;
  const int kq = fq * 8;

  for (int k0 = 0; k0 < 1024; k0 += 32) {
    // ---- stage A ----
    if constexpr (A_F16) {
      *(ushort8v*)&As[srow * 56 + scol] =
          *(const ushort8v*)((const u16*)Asel + (size_t)(m0 + srow) * 1024 + k0 + scol);
    } else {
      const float* ap = (const float*)Asel + (size_t)(m0 + srow) * 1024 + k0 + scol;
      const float4 f0 = ((const float4*)ap)[0];
      const float4 f1 = ((const float4*)ap)[1];
      ushort8v p;
      p[0] = f2h_bits(f0.x); p[1] = f2h_bits(f0.y); p[2] = f2h_bits(f0.z); p[3] = f2h_bits(f0.w);
      p[4] = f2h_bits(f1.x); p[5] = f2h_bits(f1.y); p[6] = f2h_bits(f1.z); p[7] = f2h_bits(f1.w);
      *(ushort8v*)&As[srow * 56 + scol] = p;
    }
    // ---- stage B (fp32 weights) ----
    {
      const float* bp = Bsel + (size_t)(n0 + srow) * 1024 + k0 + scol;
      const float4 f0 = ((const float4*)bp)[0];
      const float4 f1 = ((const float4*)bp)[1];
      ushort8v p;
      p[0] = f2h_bits(f0.x); p[1] = f2h_bits(f0.y); p[2] = f2h_bits(f0.z); p[3] = f2h_bits(f0.w);
      p[4] = f2h_bits(f1.x); p[5] = f2h_bits(f1.y); p[6] = f2h_bits(f1.z); p[7] = f2h_bits(f1.w);
      *(ushort8v*)&Bs[srow * 56 + scol] = p;
    }
    __syncthreads();

    half8v a[2], b[2];
#pragma unroll
    for (int m = 0; m < 2; m++)
      a[m] = *(const half8v*)&As[(wr * 32 + m * 16 + fr) * 56 + kq];
#pragma unroll
    for (int n = 0; n < 2; n++)
      b[n] = *(const half8v*)&Bs[(wc * 32 + n * 16 + fr) * 56 + kq];
#pragma unroll
    for (int m = 0; m < 2; m++)
#pragma unroll
      for (int n = 0; n < 2; n++)
        acc[m][n] = __builtin_amdgcn_mfma_f32_16x16x32_f16(a[m], b[n], acc[m][n], 0, 0, 0);
    __syncthreads();
  }

  // epilogue: C/D layout col=lane&15, row=(lane>>4)*4+reg
  u16*   Cb = (u16*)Cp   + (size_t)z * 1024 * 1024;
  float* Cf = (float*)Cp + (size_t)z * 1024 * 1024;
#pragma unroll
  for (int n = 0; n < 2; n++) {
    const int col = n0 + wc * 32 + n * 16 + fr;
    const float bn = bsel[col];
#pragma unroll
    for (int m = 0; m < 2; m++) {
      const int rbase = m0 + wr * 32 + m * 16 + fq * 4;
#pragma unroll
      for (int r = 0; r < 4; r++) {
        const float val = acc[m][n][r] + bn;
        if constexpr (OUT_F16)
          Cb[(size_t)(rbase + r) * 1024 + col] = f2h_bits(val);
        else
          Cf[(size_t)(rbase + r) * 1024 + col] = val;
      }
    }
  }
}

// ---------------------------------------------------------------------------
// Per-token bitonic sort of the 128 sample indices -> sorted u16 cols.
// ---------------------------------------------------------------------------
__global__ __launch_bounds__(128) void sort_kernel(const int* __restrict__ samples,
                                                   u16* __restrict__ cols) {
  const int row = blockIdx.x;
  const int t = threadIdx.x;
  __shared__ int s[NS];
  s[t] = samples[(size_t)row * NS + t];
  __syncthreads();

  for (unsigned k = 2; k <= NS; k <<= 1) {
    for (unsigned j = k >> 1; j > 0; j >>= 1) {
      const unsigned ixj = t ^ j;
      if (ixj > (unsigned)t) {
        const int a = s[t], b = s[ixj];
        const bool up = ((t & k) == 0);
        if ((up && a > b) || (!up && a < b)) { s[t] = b; s[ixj] = a; }
      }
      __syncthreads();
    }
  }
  cols[(size_t)row * NS + t] = (u16)s[t];
}

// ---------------------------------------------------------------------------
// Attention v4: one wave per (token, head), f16 data, dot2/pk_fma math.
//  scores: lane owns samples l, l+64; q row as 32 half2; v_dot2_f32_f16.
//  softmax: in-wave shfl_xor butterfly.
//  PV: lane = (sample-half, dim-pair); per sample one LDS uint2 broadcast
//      (row offset + duplicated-f16 weight) + one 4B V load + one v_pk_fma_f16.
// ---------------------------------------------------------------------------
__global__ __launch_bounds__(256) void attn4(const u16* __restrict__ Qb,
                                             const u16* __restrict__ Kb,
                                             const u16* __restrict__ Vb,
                                             const u16* __restrict__ cols,
                                             u16* __restrict__ O) {
  const int i = blockIdx.y;
  const int wid = threadIdx.x >> 6;
  const int h = blockIdx.x * 4 + wid;
  const int lane = threadIdx.x & 63;

  __shared__ uint2 pw[4][NS];   // per-wave: (row element offset, dup'd f16 weight)

  // ---- sample columns + dup flags ----
  const int c0 = (int)cols[(size_t)i * NS + lane];
  const int c1 = (int)cols[(size_t)i * NS + 64 + lane];
  const int cp0 = __shfl_up(c0, 1, 64);
  int cp1 = __shfl_up(c1, 1, 64);
  const int c0_63 = __builtin_amdgcn_readlane(c0, 63);
  if (lane == 0) cp1 = c0_63;
  const bool dup0 = (lane > 0) && (c0 == cp0);
  const bool dup1 = (c1 == cp1);

  // ---- q row as 32 half2 ----
  union U8 { ushort8v v; h2 h[4]; };
  U8 qu[8];
  {
    const ushort8v* qp = (const ushort8v*)(Qb + (size_t)i * EMB + h * HD);
#pragma unroll
    for (int j = 0; j < 8; j++) qu[j].v = qp[j];
  }

  // ---- scores via v_dot2_f32_f16 ----
  const ushort8v* kp0 = (const ushort8v*)(Kb + (size_t)c0 * EMB + h * HD);
  const ushort8v* kp1 = (const ushort8v*)(Kb + (size_t)c1 * EMB + h * HD);
  float s0a = 0.f, s0b = 0.f, s1a = 0.f, s1b = 0.f;
#pragma unroll
  for (int j = 0; j < 8; j++) {
    U8 k0u, k1u;
    k0u.v = kp0[j];
    k1u.v = kp1[j];
    s0a = __builtin_amdgcn_fdot2(qu[j].h[0], k0u.h[0], s0a, false);
    s0b = __builtin_amdgcn_fdot2(qu[j].h[1], k0u.h[1], s0b, false);
    s0a = __builtin_amdgcn_fdot2(qu[j].h[2], k0u.h[2], s0a, false);
    s0b = __builtin_amdgcn_fdot2(qu[j].h[3], k0u.h[3], s0b, false);
    s1a = __builtin_amdgcn_fdot2(qu[j].h[0], k1u.h[0], s1a, false);
    s1b = __builtin_amdgcn_fdot2(qu[j].h[1], k1u.h[1], s1b, false);
    s1a = __builtin_amdgcn_fdot2(qu[j].h[2], k1u.h[2], s1a, false);
    s1b = __builtin_amdgcn_fdot2(qu[j].h[3], k1u.h[3], s1b, false);
  }
  float s0 = dup0 ? -1e30f : (s0a + s0b) * 0.03125f;  // 1/sqrt(1024)
  float s1 = dup1 ? -1e30f : (s1a + s1b) * 0.03125f;

  // ---- in-wave softmax over 128 values ----
  float mx = fmaxf(s0, s1);
#pragma unroll
  for (int off = 32; off > 0; off >>= 1) mx = fmaxf(mx, __shfl_xor(mx, off, 64));
  const float e0 = __expf(s0 - mx);
  const float e1 = __expf(s1 - mx);
  float sm = e0 + e1;
#pragma unroll
  for (int off = 32; off > 0; off >>= 1) sm += __shfl_xor(sm, off, 64);
  const float inv = 1.0f / sm;

  // ---- publish (offset, weight) pairs to LDS (same-wave visibility) ----
  pw[wid][lane]      = make_uint2((uint)c0 * EMB, (uint)f2h_bits(e0 * inv) * 0x10001u);
  pw[wid][64 + lane] = make_uint2((uint)c1 * EMB, (uint)f2h_bits(e1 * inv) * 0x10001u);

  // ---- PV: lane = (sample-half, dim-pair), packed f16 FMA ----
  const int half = lane >> 5;
  const int dp = lane & 31;
  const uint boff = (uint)(h * HD + 2 * dp);
  const uint2* pwp = &pw[wid][half * 64];
  h2 acc = (h2){(_Float16)0.f, (_Float16)0.f};
#pragma unroll 8
  for (int s = 0; s < 64; s++) {
    const uint2 e = pwp[s];
    union { uint u; h2 h; } v, ww;
    v.u = *(const uint*)(Vb + e.x + boff);
    ww.u = e.y;
    acc += v.h * ww.h;
  }
  float o0 = (float)acc[0];
  float o1 = (float)acc[1];
  o0 += __shfl_xor(o0, 32, 64);
  o1 += __shfl_xor(o1, 32, 64);
  if (lane < 32) {
    const uint ob = (uint)f2h_bits(o0) | ((uint)f2h_bits(o1) << 16);
    *(uint*)(O + (size_t)i * EMB + h * HD + 2 * dp) = ob;
  }
}

extern "C" void kernel_launch(void* const* d_in, const int* in_sizes, int n_in,
                              void* d_out, int out_size, void* d_ws, size_t ws_size,
                              hipStream_t stream) {
  const float* query = (const float*)d_in[0];
  const float* key   = (const float*)d_in[1];
  const float* value = (const float*)d_in[2];
  const float* Wq    = (const float*)d_in[3];
  const float* bq    = (const float*)d_in[4];
  const float* Wk    = (const float*)d_in[5];
  const float* bk    = (const float*)d_in[6];
  const float* Wv    = (const float*)d_in[7];
  const float* bv    = (const float*)d_in[8];
  const float* Wo    = (const float*)d_in[9];
  const float* bo    = (const float*)d_in[10];
  const int* samples = (const int*)d_in[11];
  float* out = (float*)d_out;

  // ws layout (f16): Qh,Kh,Vh,O 2MB each + cols 0.25MB = 8.25 MB total
  u16* Qh = (u16*)d_ws;
  u16* Kh = Qh + (size_t)NTOK * EMB;
  u16* Vh = Kh + (size_t)NTOK * EMB;
  u16* O  = Vh + (size_t)NTOK * EMB;
  u16* cols = O + (size_t)NTOK * EMB;

  sort_kernel<<<NTOK, NS, 0, stream>>>(samples, cols);

  gemm_t64<false, true><<<dim3(16, 16, 3), 256, 0, stream>>>(
      query, key, value, Wq, Wk, Wv, bq, bk, bv, Qh);

  attn4<<<dim3(NH / 4, NTOK), 256, 0, stream>>>(Qh, Kh, Vh, cols, O);

  gemm_t64<true, false><<<dim3(16, 16, 1), 256, 0, stream>>>(
      O, O, O, Wo, Wo, Wo, bo, bo, bo, out);
}